// Round 12
// baseline (334.618 us; speedup 1.0000x reference)
//
#include <hip/hip_runtime.h>
#include <hip/hip_bf16.h>

#define N_ATOMS 50000
#define DEG 16
#define N_MOL 1000
#define NA 23
#define NB 7
#define O0 32
#define O1 12
#define O2 8
#define OT 52          // 32+12+8
#define SROW 128       // s-row: 108 used + pad, bf16 (raw ushort bits)
#define NPW 4          // nodes per wave in k2
#define WFRAG_N 1792   // 28 fragments * 64 lanes, short8 each (28672 B)

// s-row layout (bf16 bits, index t):
//  [0,32)   s0[o]        [32,44) s1.x   [44,56) s1.y   [56,68) s1.z
//  [68,76)  s2.m0  [76,84) s2.m1  [84,92) s2.m2  [92,100) s2.m3  [100,108) s2.m4

typedef __attribute__((ext_vector_type(8))) short short8;
typedef __attribute__((ext_vector_type(4))) float floatx4;

__device__ __forceinline__ unsigned short bfbits(float f) {  // f32 -> bf16 RNE
    unsigned u = __float_as_uint(f);
    u += 0x7FFFu + ((u >> 16) & 1u);
    return (unsigned short)(u >> 16);
}
__device__ __forceinline__ float bf_lo(unsigned u) { return __uint_as_float(u << 16); }
__device__ __forceinline__ float bf_hi(unsigned u) { return __uint_as_float(u & 0xFFFF0000u); }
__device__ __forceinline__ float wred4(float v) {  // sum over the 4 quads
    v += __shfl_xor(v, 16, 64); v += __shfl_xor(v, 32, 64); return v;
}

// ---------------- K_prep: zero out + W1 -> fragment-ordered table ------------
__global__ void k_prep(const float* __restrict__ W1_0, const float* __restrict__ W1_1,
                       const float* __restrict__ W1_2, unsigned short* __restrict__ Wfrag,
                       float* __restrict__ out) {
    int idx = blockIdx.x * 256 + threadIdx.x;
    if (idx < N_MOL) out[idx] = 0.0f;
    if (idx >= WFRAG_N * 8) return;
    int j    = idx & 7;
    int lane = (idx >> 3) & 63;
    int st   = idx >> 9;           // 0..27 = s*4+t
    int s = st >> 2, t = st & 3;
    int a = (lane >> 4) * 8 + j, o = t * 16 + (lane & 15);
    float val = 0.f;
    if (a < NA && o < OT) {
        const float n1 = 0.07881104062391006f; // 1/sqrt(23*7)
        if (o < O0)           val = W1_0[(a * NB + s) * O0 + o] * n1;
        else if (o < O0 + O1) val = W1_1[(a * NB + s) * O1 + (o - O0)] * n1;
        else                  val = W1_2[(a * NB + s) * O2 + (o - O0 - O1)] * n1;
    }
    Wfrag[idx] = bfbits(val);
}

// ---------------- K2: per-node MFMA GEMM; 512-thread blocks ------------------
// R11 lesson: 256-thread blocks cap at 16 waves/CU (LDS 30.7KB serves only 4
// waves). 512-thread blocks share the 28.7KB wfrag across 8 waves: 4 blocks/CU
// = 32 waves/CU = 100% occupancy cap (VGPR 52 <= 64-cap at 8 waves/SIMD).
__global__ __launch_bounds__(512, 8) void k2_s(const float* __restrict__ pos,
        const float* __restrict__ x, const float* __restrict__ edge_attr,
        const int* __restrict__ edge_src, const unsigned short* __restrict__ Wfrag,
        unsigned short* __restrict__ sbuf) {
    __shared__ short8 wfrag[WFRAG_N];          // 28672 B, shared by 8 waves
    __shared__ float hbuf[8][16][8];
    const int tid  = threadIdx.x;
    const int wid  = tid >> 6;                  // 0..7
    const int lane = tid & 63;
    const int lcol = lane & 15;
    const int quad = lane >> 4;

    {   // cooperative stage of the prebuilt weight fragments (coalesced)
        uint4* dst = (uint4*)wfrag;
        const uint4* src4 = (const uint4*)Wfrag;
        for (int i = tid; i < WFRAG_N; i += 512) dst[i] = src4[i];
    }
    __syncthreads();

    const int wgid = __builtin_amdgcn_readfirstlane(blockIdx.x * 8 + wid);
    const int base = wgid * NPW;
    if (base >= N_ATOMS) return;

    float (*hb)[8] = hbuf[wid];
    const float s3 = 1.7320508075688772f, s15 = 3.872983346207417f;
    const float s5h = 1.118033988749895f, s15h = 1.9364916731037085f;

    auto clampn = [&](int i) { int nn = base + i; return nn < N_ATOMS ? nn : N_ATOMS - 1; };
    int s0v = edge_src[clampn(0) * DEG + lcol];
    int s1v = edge_src[clampn(1) * DEG + lcol];
    float x0[8], e0v[NB];
    float p0x, p0y, p0z;
    #pragma unroll
    for (int j = 0; j < 8; j++) { int a = quad * 8 + j; x0[j] = (a < NA) ? x[s0v * NA + a] : 0.f; }
    {
        const float* p = edge_attr + ((size_t)clampn(0) * DEG + lcol) * NB;
        #pragma unroll
        for (int b = 0; b < NB; b++) e0v[b] = p[b];
    }
    p0x = pos[s0v * 3 + 0]; p0y = pos[s0v * 3 + 1]; p0z = pos[s0v * 3 + 2];

    #pragma unroll 1
    for (int i = 0; i < NPW; i++) {
        const int n = base + i;
        if (n >= N_ATOMS) break;
        // ---- prefetch next stage (1 deep: x, ea, pos(src)) ----
        int s2v = edge_src[clampn(i + 2 < NPW ? i + 2 : i) * DEG + lcol];
        float x1[8], e1v[NB], p1x, p1y, p1z;
        #pragma unroll
        for (int j = 0; j < 8; j++) { int a = quad * 8 + j; x1[j] = (a < NA) ? x[s1v * NA + a] : 0.f; }
        {
            const float* p = edge_attr + ((size_t)clampn(i + 1 < NPW ? i + 1 : i) * DEG + lcol) * NB;
            #pragma unroll
            for (int b = 0; b < NB; b++) e1v[b] = p[b];
        }
        p1x = pos[s1v * 3 + 0]; p1y = pos[s1v * 3 + 1]; p1z = pos[s1v * 3 + 2];

        // ---- h-factors for node n (lanes 0..15; pos(src) already in regs) ----
        const float pdx = pos[n * 3 + 0], pdy = pos[n * 3 + 1], pdz = pos[n * 3 + 2];
        if (lane < 16) {
            const float vx = p0x - pdx, vy = p0y - pdy, vz = p0z - pdz;
            hb[lane][0] = s3 * vx;  hb[lane][1] = s3 * vy;  hb[lane][2] = s3 * vz;
            hb[lane][3] = s15 * vx * vy;
            hb[lane][4] = s15 * vy * vz;
            hb[lane][5] = s5h * (2.f * vz * vz - vx * vx - vy * vy);
            hb[lane][6] = s15 * vx * vz;
            hb[lane][7] = s15h * (vx * vx - vy * vy);
        }
        // ---- MFMA: 7 K-steps x 4 N-tiles ----
        floatx4 acc0 = {0.f,0.f,0.f,0.f}, acc1 = {0.f,0.f,0.f,0.f};
        floatx4 acc2 = {0.f,0.f,0.f,0.f}, acc3 = {0.f,0.f,0.f,0.f};
        #pragma unroll
        for (int s = 0; s < 7; s++) {
            const float eb = e0v[s];
            union { short8 v; unsigned u[4]; } af;
            #pragma unroll
            for (int j = 0; j < 8; j += 2) {
                float2 pr; pr.x = x0[j] * eb; pr.y = x0[j + 1] * eb;
                __hip_bfloat162 bb = __float22bfloat162_rn(pr);
                af.u[j >> 1] = *(unsigned*)&bb;
            }
            acc0 = __builtin_amdgcn_mfma_f32_16x16x32_bf16(af.v, wfrag[(s*4+0)*64 + lane], acc0, 0, 0, 0);
            acc1 = __builtin_amdgcn_mfma_f32_16x16x32_bf16(af.v, wfrag[(s*4+1)*64 + lane], acc1, 0, 0, 0);
            acc2 = __builtin_amdgcn_mfma_f32_16x16x32_bf16(af.v, wfrag[(s*4+2)*64 + lane], acc2, 0, 0, 0);
            acc3 = __builtin_amdgcn_mfma_f32_16x16x32_bf16(af.v, wfrag[(s*4+3)*64 + lane], acc3, 0, 0, 0);
        }
        // ---- epilogue (layout verified R4): lane's D-edges are e = quad*4+r ----
        float4 hA[4], hB[4];
        #pragma unroll
        for (int r = 0; r < 4; r++) {
            int e = quad * 4 + r;
            hA[r] = *(const float4*)&hb[e][0];
            hB[r] = *(const float4*)&hb[e][4];
        }
        const float q = 0.25f; // inv_sqrt_deg
        unsigned short* sr = sbuf + (size_t)n * SROW;
        float v0 = wred4(acc0[0] + acc0[1] + acc0[2] + acc0[3]);
        float v1 = wred4(acc1[0] + acc1[1] + acc1[2] + acc1[3]);
        if (quad == 0) { sr[lcol] = bfbits(v0 * q); sr[16 + lcol] = bfbits(v1 * q); }
        if (lcol < 12) {
            float t0 = 0.f, t1 = 0.f, t2 = 0.f;
            #pragma unroll
            for (int r = 0; r < 4; r++) {
                float m = acc2[r];
                t0 += m * hA[r].x; t1 += m * hA[r].y; t2 += m * hA[r].z;
            }
            t0 = wred4(t0); t1 = wred4(t1); t2 = wred4(t2);
            if (quad == 0) {
                sr[32 + lcol] = bfbits(t0 * q);
                sr[44 + lcol] = bfbits(t1 * q);
                sr[56 + lcol] = bfbits(t2 * q);
            }
        } else {
            int a = lcol - 12;
            float t0 = 0.f, t1 = 0.f, t2 = 0.f, t3 = 0.f, t4 = 0.f;
            #pragma unroll
            for (int r = 0; r < 4; r++) {
                float m = acc2[r];
                t0 += m * hA[r].w; t1 += m * hB[r].x; t2 += m * hB[r].y;
                t3 += m * hB[r].z; t4 += m * hB[r].w;
            }
            t0 = wred4(t0); t1 = wred4(t1); t2 = wred4(t2); t3 = wred4(t3); t4 = wred4(t4);
            if (quad == 0) {
                sr[68 + a] = bfbits(t0 * q); sr[76 + a] = bfbits(t1 * q);
                sr[84 + a] = bfbits(t2 * q); sr[92 + a] = bfbits(t3 * q);
                sr[100 + a] = bfbits(t4 * q);
            }
        }
        if (lcol < 4) {
            int a = lcol + 4;
            float t0 = 0.f, t1 = 0.f, t2 = 0.f, t3 = 0.f, t4 = 0.f;
            #pragma unroll
            for (int r = 0; r < 4; r++) {
                float m = acc3[r];
                t0 += m * hA[r].w; t1 += m * hB[r].x; t2 += m * hB[r].y;
                t3 += m * hB[r].z; t4 += m * hB[r].w;
            }
            t0 = wred4(t0); t1 = wred4(t1); t2 = wred4(t2); t3 = wred4(t3); t4 = wred4(t4);
            if (quad == 0) {
                sr[68 + a] = bfbits(t0 * q); sr[76 + a] = bfbits(t1 * q);
                sr[84 + a] = bfbits(t2 * q); sr[92 + a] = bfbits(t3 * q);
                sr[100 + a] = bfbits(t4 * q);
            }
        }
        // ---- rotate pipeline ----
        s0v = s1v; s1v = s2v;
        #pragma unroll
        for (int j = 0; j < 8; j++) x0[j] = x1[j];
        #pragma unroll
        for (int b = 0; b < NB; b++) e0v[b] = e1v[b];
        p0x = p1x; p0y = p1y; p0z = p1z;
    }
}

// ---------------- K3f: R7 body; 7 blocks/CU for gather-latency hiding --------
__global__ __launch_bounds__(256, 7) void k3_fused(const float* __restrict__ pos,
        const float* __restrict__ edge_attr, const int* __restrict__ edge_src,
        const unsigned short* __restrict__ sbuf,
        const float* __restrict__ W2_0, const float* __restrict__ W2_1,
        const float* __restrict__ W2_2, float* __restrict__ out) {
    __shared__ float ea_t[4][4][16][8];    // [wave][node][edge][b(7)+pad]
    __shared__ float hbf[4][4][192];       // [wave][node][edge*12 + code(9 used)]
    const int tid  = threadIdx.x;
    const int wid  = tid >> 6;
    const int lane = tid & 63;
    const int q    = lane >> 4;
    const int e    = lane & 15;
    const int base = __builtin_amdgcn_readfirstlane(blockIdx.x * 4 + wid) * 4;

    const float c0 = 0.06681531047810609f;  // 1/sqrt(32*7)
    const float c1 = 0.06299407883487121f;  // 1/sqrt(12*7*3)
    const float c2 = 0.05976143046671968f;  // 1/sqrt(8*7*5)
    int code = 0, aA = 0, aB = 0, valid = 1;
    const float* Wb = W2_0; float norm = c0;
    const int j = lane;
    if (j < 16)      { code = 0; aA = 2 * j;   aB = aA + 1; Wb = W2_0; norm = c0; }
    else if (j < 34) { int g = (j - 16) / 6, r = (j - 16) - 6 * g;
                       code = 1 + g; aA = 2 * r; aB = aA + 1; Wb = W2_1; norm = c1; }
    else if (j < 54) { int g = (j - 34) >> 2, r = (j - 34) & 3;
                       code = 4 + g; aA = 2 * r; aB = aA + 1; Wb = W2_2; norm = c2; }
    else             { valid = 0; }
    float wA[NB], wB[NB];
    #pragma unroll
    for (int b = 0; b < NB; b++) {
        wA[b] = valid ? Wb[aA * NB + b] * norm : 0.f;
        wB[b] = valid ? Wb[aB * NB + b] * norm : 0.f;
    }
    const int jj = valid ? j : 0;

    // ---- setup phase: all 64 lanes stage (node q, edge e) ----
    {
        const int nq = base + q;
        const int sE = edge_src[nq * DEG + e];                 // vector load
        const float* eap = edge_attr + ((size_t)nq * DEG + e) * NB;
        float ev[8];
        #pragma unroll
        for (int b = 0; b < NB; b++) ev[b] = eap[b];
        ev[7] = 0.f;
        const float vx = pos[sE * 3 + 0] - pos[nq * 3 + 0];
        const float vy = pos[sE * 3 + 1] - pos[nq * 3 + 1];
        const float vz = pos[sE * 3 + 2] - pos[nq * 3 + 2];
        float* ed = &ea_t[wid][q][e][0];
        *(float4*)(ed)     = *(float4*)&ev[0];
        *(float4*)(ed + 4) = *(float4*)&ev[4];
        const float s3 = 1.7320508075688772f, s15 = 3.872983346207417f;
        const float s5h = 1.118033988749895f, s15h = 1.9364916731037085f;
        float* hr = &hbf[wid][q][e * 12];
        hr[0] = 1.0f;
        hr[1] = s3 * vx; hr[2] = s3 * vy; hr[3] = s3 * vz;
        hr[4] = s15 * vx * vy;
        hr[5] = s15 * vy * vz;
        hr[6] = s5h * (2.f * vz * vz - vx * vx - vy * vy);
        hr[7] = s15 * vx * vz;
        hr[8] = s15h * (vx * vx - vy * vy);
    }
    // in-wave LDS ordering: this wave's ds_writes precede its ds_reads.

    // ---- gather pipeline (2 deep) ----
    const int* srcp = edge_src + (size_t)base * DEG;           // uniform base
    unsigned g0[DEG], g1[DEG];
    #pragma unroll
    for (int k = 0; k < DEG; k++) {
        int s = __builtin_amdgcn_readfirstlane(srcp[k]);       // s_load
        g0[k] = *(const unsigned*)(sbuf + (size_t)s * SROW + 2 * jj);
    }
    #pragma unroll
    for (int i = 0; i < 4; i++) {
        if (i + 1 < 4) {
            #pragma unroll
            for (int k = 0; k < DEG; k++) {
                int s = __builtin_amdgcn_readfirstlane(srcp[(i + 1) * DEG + k]);
                g1[k] = *(const unsigned*)(sbuf + (size_t)s * SROW + 2 * jj);
            }
        }
        const float* hw = &hbf[wid][i][0];
        float acc = 0.f;
        #pragma unroll
        for (int k = 0; k < DEG; k++) {
            const float4 eA = *(const float4*)&ea_t[wid][i][k][0];  // broadcast
            const float4 eB = *(const float4*)&ea_t[wid][i][k][4];
            const float f = hw[k * 12 + code];                      // 9 banks, no conflict
            float we0 = eA.x * wA[0] + eA.y * wA[1] + eA.z * wA[2] + eA.w * wA[3]
                      + eB.x * wA[4] + eB.y * wA[5] + eB.z * wA[6];
            float we1 = eA.x * wB[0] + eA.y * wB[1] + eA.z * wB[2] + eA.w * wB[3]
                      + eB.x * wB[4] + eB.y * wB[5] + eB.z * wB[6];
            acc += f * (bf_lo(g0[k]) * we0 + bf_hi(g0[k]) * we1);
        }
        acc = valid ? acc : 0.f;
        #pragma unroll
        for (int off = 32; off >= 1; off >>= 1) acc += __shfl_xor(acc, off, 64);
        if (lane == 0)
            atomicAdd(out + ((base + i) / 50), acc * 0.035355339059327376f); // 0.25/sqrt(50)
        #pragma unroll
        for (int k = 0; k < DEG; k++) g0[k] = g1[k];
    }
}

extern "C" void kernel_launch(void* const* d_in, const int* in_sizes, int n_in,
                              void* d_out, int out_size, void* d_ws, size_t ws_size,
                              hipStream_t stream) {
    const float* pos  = (const float*)d_in[0];
    const float* x    = (const float*)d_in[1];
    const float* ea   = (const float*)d_in[2];
    const float* W1_0 = (const float*)d_in[3];
    const float* W1_1 = (const float*)d_in[4];
    const float* W1_2 = (const float*)d_in[5];
    const float* W2_0 = (const float*)d_in[6];
    const float* W2_1 = (const float*)d_in[7];
    const float* W2_2 = (const float*)d_in[8];
    const int*   esrc = (const int*)d_in[9];
    float* out = (float*)d_out;

    unsigned short* Wfrag = (unsigned short*)d_ws;                   // 28672 B
    unsigned short* sbuf  = (unsigned short*)((char*)d_ws + 32768);  // 12.8 MB

    hipLaunchKernelGGL(k_prep, dim3(WFRAG_N * 8 / 256), dim3(256), 0, stream,
                       W1_0, W1_1, W1_2, Wfrag, out);
    hipLaunchKernelGGL(k2_s, dim3((N_ATOMS / NPW + 7) / 8), dim3(512), 0, stream,
                       pos, x, ea, esrc, Wfrag, sbuf);
    hipLaunchKernelGGL(k3_fused, dim3(N_ATOMS / 16), dim3(256), 0, stream,
                       pos, ea, esrc, sbuf, W2_0, W2_1, W2_2, out);
}

// Round 13
// 208.128 us; speedup vs baseline: 1.6078x; 1.6078x over previous
//
#include <hip/hip_runtime.h>
#include <hip/hip_bf16.h>

#define N_ATOMS 50000
#define DEG 16
#define N_MOL 1000
#define NA 23
#define NB 7
#define O0 32
#define O1 12
#define O2 8
#define OT 52          // 32+12+8
#define SROW 128       // s-row: 108 used + pad, bf16 (raw ushort bits)
#define NPW 4          // nodes per wave in k2
#define WFRAG_N 1792   // 28 fragments * 64 lanes, short8 each (28672 B)

// s-row layout (bf16 bits, index t):
//  [0,32)   s0[o]        [32,44) s1.x   [44,56) s1.y   [56,68) s1.z
//  [68,76)  s2.m0  [76,84) s2.m1  [84,92) s2.m2  [92,100) s2.m3  [100,108) s2.m4

typedef __attribute__((ext_vector_type(8))) short short8;
typedef __attribute__((ext_vector_type(4))) float floatx4;

__device__ __forceinline__ unsigned short bfbits(float f) {  // f32 -> bf16 RNE
    unsigned u = __float_as_uint(f);
    u += 0x7FFFu + ((u >> 16) & 1u);
    return (unsigned short)(u >> 16);
}
__device__ __forceinline__ float bf_lo(unsigned u) { return __uint_as_float(u << 16); }
__device__ __forceinline__ float bf_hi(unsigned u) { return __uint_as_float(u & 0xFFFF0000u); }
__device__ __forceinline__ float wred4(float v) {  // sum over the 4 quads
    v += __shfl_xor(v, 16, 64); v += __shfl_xor(v, 32, 64); return v;
}

// ---------------- K_prep: zero out + W1 -> fragment-ordered table ------------
__global__ void k_prep(const float* __restrict__ W1_0, const float* __restrict__ W1_1,
                       const float* __restrict__ W1_2, unsigned short* __restrict__ Wfrag,
                       float* __restrict__ out) {
    int idx = blockIdx.x * 256 + threadIdx.x;
    if (idx < N_MOL) out[idx] = 0.0f;
    if (idx >= WFRAG_N * 8) return;
    int j    = idx & 7;
    int lane = (idx >> 3) & 63;
    int st   = idx >> 9;           // 0..27 = s*4+t
    int s = st >> 2, t = st & 3;
    int a = (lane >> 4) * 8 + j, o = t * 16 + (lane & 15);
    float val = 0.f;
    if (a < NA && o < OT) {
        const float n1 = 0.07881104062391006f; // 1/sqrt(23*7)
        if (o < O0)           val = W1_0[(a * NB + s) * O0 + o] * n1;
        else if (o < O0 + O1) val = W1_1[(a * NB + s) * O1 + (o - O0)] * n1;
        else                  val = W1_2[(a * NB + s) * O2 + (o - O0 - O1)] * n1;
    }
    Wfrag[idx] = bfbits(val);
}

// ---------------- K2: per-node MFMA GEMM; R11 body; 5 blocks/CU --------------
// R8/R12 lesson: this body needs ~52 VGPR. Any launch_bounds whose VGPR cap
// (512/waves_per_EU) is below that spills catastrophically. (256,5): cap=102,
// LDS 30.72KB x 5 = 153.6KB <= 160KB -> 5 blocks/CU, 20 waves/CU.
__global__ __launch_bounds__(256, 5) void k2_s(const float* __restrict__ pos,
        const float* __restrict__ x, const float* __restrict__ edge_attr,
        const int* __restrict__ edge_src, const unsigned short* __restrict__ Wfrag,
        unsigned short* __restrict__ sbuf) {
    __shared__ short8 wfrag[WFRAG_N];          // 28672 B, shared by 4 waves
    __shared__ float hbuf[4][16][8];
    const int tid  = threadIdx.x;
    const int wid  = tid >> 6;
    const int lane = tid & 63;
    const int lcol = lane & 15;
    const int quad = lane >> 4;

    {   // cooperative stage of the prebuilt weight fragments (coalesced)
        uint4* dst = (uint4*)wfrag;
        const uint4* src4 = (const uint4*)Wfrag;
        for (int i = tid; i < WFRAG_N; i += 256) dst[i] = src4[i];
    }
    __syncthreads();

    const int wgid = __builtin_amdgcn_readfirstlane(blockIdx.x * 4 + wid);
    const int base = wgid * NPW;
    if (base >= N_ATOMS) return;

    float (*hb)[8] = hbuf[wid];
    const float s3 = 1.7320508075688772f, s15 = 3.872983346207417f;
    const float s5h = 1.118033988749895f, s15h = 1.9364916731037085f;

    auto clampn = [&](int i) { int nn = base + i; return nn < N_ATOMS ? nn : N_ATOMS - 1; };
    int s0v = edge_src[clampn(0) * DEG + lcol];
    int s1v = edge_src[clampn(1) * DEG + lcol];
    float x0[8], e0v[NB];
    float p0x, p0y, p0z;
    #pragma unroll
    for (int j = 0; j < 8; j++) { int a = quad * 8 + j; x0[j] = (a < NA) ? x[s0v * NA + a] : 0.f; }
    {
        const float* p = edge_attr + ((size_t)clampn(0) * DEG + lcol) * NB;
        #pragma unroll
        for (int b = 0; b < NB; b++) e0v[b] = p[b];
    }
    p0x = pos[s0v * 3 + 0]; p0y = pos[s0v * 3 + 1]; p0z = pos[s0v * 3 + 2];

    #pragma unroll 1
    for (int i = 0; i < NPW; i++) {
        const int n = base + i;
        if (n >= N_ATOMS) break;
        // ---- prefetch next stage (1 deep: x, ea, pos(src)) ----
        int s2v = edge_src[clampn(i + 2 < NPW ? i + 2 : i) * DEG + lcol];
        float x1[8], e1v[NB], p1x, p1y, p1z;
        #pragma unroll
        for (int j = 0; j < 8; j++) { int a = quad * 8 + j; x1[j] = (a < NA) ? x[s1v * NA + a] : 0.f; }
        {
            const float* p = edge_attr + ((size_t)clampn(i + 1 < NPW ? i + 1 : i) * DEG + lcol) * NB;
            #pragma unroll
            for (int b = 0; b < NB; b++) e1v[b] = p[b];
        }
        p1x = pos[s1v * 3 + 0]; p1y = pos[s1v * 3 + 1]; p1z = pos[s1v * 3 + 2];

        // ---- h-factors for node n (lanes 0..15; pos(src) already in regs) ----
        const float pdx = pos[n * 3 + 0], pdy = pos[n * 3 + 1], pdz = pos[n * 3 + 2];
        if (lane < 16) {
            const float vx = p0x - pdx, vy = p0y - pdy, vz = p0z - pdz;
            hb[lane][0] = s3 * vx;  hb[lane][1] = s3 * vy;  hb[lane][2] = s3 * vz;
            hb[lane][3] = s15 * vx * vy;
            hb[lane][4] = s15 * vy * vz;
            hb[lane][5] = s5h * (2.f * vz * vz - vx * vx - vy * vy);
            hb[lane][6] = s15 * vx * vz;
            hb[lane][7] = s15h * (vx * vx - vy * vy);
        }
        // ---- MFMA: 7 K-steps x 4 N-tiles ----
        floatx4 acc0 = {0.f,0.f,0.f,0.f}, acc1 = {0.f,0.f,0.f,0.f};
        floatx4 acc2 = {0.f,0.f,0.f,0.f}, acc3 = {0.f,0.f,0.f,0.f};
        #pragma unroll
        for (int s = 0; s < 7; s++) {
            const float eb = e0v[s];
            union { short8 v; unsigned u[4]; } af;
            #pragma unroll
            for (int j = 0; j < 8; j += 2) {
                float2 pr; pr.x = x0[j] * eb; pr.y = x0[j + 1] * eb;
                __hip_bfloat162 bb = __float22bfloat162_rn(pr);
                af.u[j >> 1] = *(unsigned*)&bb;
            }
            acc0 = __builtin_amdgcn_mfma_f32_16x16x32_bf16(af.v, wfrag[(s*4+0)*64 + lane], acc0, 0, 0, 0);
            acc1 = __builtin_amdgcn_mfma_f32_16x16x32_bf16(af.v, wfrag[(s*4+1)*64 + lane], acc1, 0, 0, 0);
            acc2 = __builtin_amdgcn_mfma_f32_16x16x32_bf16(af.v, wfrag[(s*4+2)*64 + lane], acc2, 0, 0, 0);
            acc3 = __builtin_amdgcn_mfma_f32_16x16x32_bf16(af.v, wfrag[(s*4+3)*64 + lane], acc3, 0, 0, 0);
        }
        // ---- epilogue (layout verified R4): lane's D-edges are e = quad*4+r ----
        float4 hA[4], hB[4];
        #pragma unroll
        for (int r = 0; r < 4; r++) {
            int e = quad * 4 + r;
            hA[r] = *(const float4*)&hb[e][0];
            hB[r] = *(const float4*)&hb[e][4];
        }
        const float q = 0.25f; // inv_sqrt_deg
        unsigned short* sr = sbuf + (size_t)n * SROW;
        float v0 = wred4(acc0[0] + acc0[1] + acc0[2] + acc0[3]);
        float v1 = wred4(acc1[0] + acc1[1] + acc1[2] + acc1[3]);
        if (quad == 0) { sr[lcol] = bfbits(v0 * q); sr[16 + lcol] = bfbits(v1 * q); }
        if (lcol < 12) {
            float t0 = 0.f, t1 = 0.f, t2 = 0.f;
            #pragma unroll
            for (int r = 0; r < 4; r++) {
                float m = acc2[r];
                t0 += m * hA[r].x; t1 += m * hA[r].y; t2 += m * hA[r].z;
            }
            t0 = wred4(t0); t1 = wred4(t1); t2 = wred4(t2);
            if (quad == 0) {
                sr[32 + lcol] = bfbits(t0 * q);
                sr[44 + lcol] = bfbits(t1 * q);
                sr[56 + lcol] = bfbits(t2 * q);
            }
        } else {
            int a = lcol - 12;
            float t0 = 0.f, t1 = 0.f, t2 = 0.f, t3 = 0.f, t4 = 0.f;
            #pragma unroll
            for (int r = 0; r < 4; r++) {
                float m = acc2[r];
                t0 += m * hA[r].w; t1 += m * hB[r].x; t2 += m * hB[r].y;
                t3 += m * hB[r].z; t4 += m * hB[r].w;
            }
            t0 = wred4(t0); t1 = wred4(t1); t2 = wred4(t2); t3 = wred4(t3); t4 = wred4(t4);
            if (quad == 0) {
                sr[68 + a] = bfbits(t0 * q); sr[76 + a] = bfbits(t1 * q);
                sr[84 + a] = bfbits(t2 * q); sr[92 + a] = bfbits(t3 * q);
                sr[100 + a] = bfbits(t4 * q);
            }
        }
        if (lcol < 4) {
            int a = lcol + 4;
            float t0 = 0.f, t1 = 0.f, t2 = 0.f, t3 = 0.f, t4 = 0.f;
            #pragma unroll
            for (int r = 0; r < 4; r++) {
                float m = acc3[r];
                t0 += m * hA[r].w; t1 += m * hB[r].x; t2 += m * hB[r].y;
                t3 += m * hB[r].z; t4 += m * hB[r].w;
            }
            t0 = wred4(t0); t1 = wred4(t1); t2 = wred4(t2); t3 = wred4(t3); t4 = wred4(t4);
            if (quad == 0) {
                sr[68 + a] = bfbits(t0 * q); sr[76 + a] = bfbits(t1 * q);
                sr[84 + a] = bfbits(t2 * q); sr[92 + a] = bfbits(t3 * q);
                sr[100 + a] = bfbits(t4 * q);
            }
        }
        // ---- rotate pipeline ----
        s0v = s1v; s1v = s2v;
        #pragma unroll
        for (int j = 0; j < 8; j++) x0[j] = x1[j];
        #pragma unroll
        for (int b = 0; b < NB; b++) e0v[b] = e1v[b];
        p0x = p1x; p0y = p1y; p0z = p1z;
    }
}

// ---------------- K3f: R7 body; 7 blocks/CU for gather-latency hiding --------
__global__ __launch_bounds__(256, 7) void k3_fused(const float* __restrict__ pos,
        const float* __restrict__ edge_attr, const int* __restrict__ edge_src,
        const unsigned short* __restrict__ sbuf,
        const float* __restrict__ W2_0, const float* __restrict__ W2_1,
        const float* __restrict__ W2_2, float* __restrict__ out) {
    __shared__ float ea_t[4][4][16][8];    // [wave][node][edge][b(7)+pad]
    __shared__ float hbf[4][4][192];       // [wave][node][edge*12 + code(9 used)]
    const int tid  = threadIdx.x;
    const int wid  = tid >> 6;
    const int lane = tid & 63;
    const int q    = lane >> 4;
    const int e    = lane & 15;
    const int base = __builtin_amdgcn_readfirstlane(blockIdx.x * 4 + wid) * 4;

    const float c0 = 0.06681531047810609f;  // 1/sqrt(32*7)
    const float c1 = 0.06299407883487121f;  // 1/sqrt(12*7*3)
    const float c2 = 0.05976143046671968f;  // 1/sqrt(8*7*5)
    int code = 0, aA = 0, aB = 0, valid = 1;
    const float* Wb = W2_0; float norm = c0;
    const int j = lane;
    if (j < 16)      { code = 0; aA = 2 * j;   aB = aA + 1; Wb = W2_0; norm = c0; }
    else if (j < 34) { int g = (j - 16) / 6, r = (j - 16) - 6 * g;
                       code = 1 + g; aA = 2 * r; aB = aA + 1; Wb = W2_1; norm = c1; }
    else if (j < 54) { int g = (j - 34) >> 2, r = (j - 34) & 3;
                       code = 4 + g; aA = 2 * r; aB = aA + 1; Wb = W2_2; norm = c2; }
    else             { valid = 0; }
    float wA[NB], wB[NB];
    #pragma unroll
    for (int b = 0; b < NB; b++) {
        wA[b] = valid ? Wb[aA * NB + b] * norm : 0.f;
        wB[b] = valid ? Wb[aB * NB + b] * norm : 0.f;
    }
    const int jj = valid ? j : 0;

    // ---- setup phase: all 64 lanes stage (node q, edge e) ----
    {
        const int nq = base + q;
        const int sE = edge_src[nq * DEG + e];                 // vector load
        const float* eap = edge_attr + ((size_t)nq * DEG + e) * NB;
        float ev[8];
        #pragma unroll
        for (int b = 0; b < NB; b++) ev[b] = eap[b];
        ev[7] = 0.f;
        const float vx = pos[sE * 3 + 0] - pos[nq * 3 + 0];
        const float vy = pos[sE * 3 + 1] - pos[nq * 3 + 1];
        const float vz = pos[sE * 3 + 2] - pos[nq * 3 + 2];
        float* ed = &ea_t[wid][q][e][0];
        *(float4*)(ed)     = *(float4*)&ev[0];
        *(float4*)(ed + 4) = *(float4*)&ev[4];
        const float s3 = 1.7320508075688772f, s15 = 3.872983346207417f;
        const float s5h = 1.118033988749895f, s15h = 1.9364916731037085f;
        float* hr = &hbf[wid][q][e * 12];
        hr[0] = 1.0f;
        hr[1] = s3 * vx; hr[2] = s3 * vy; hr[3] = s3 * vz;
        hr[4] = s15 * vx * vy;
        hr[5] = s15 * vy * vz;
        hr[6] = s5h * (2.f * vz * vz - vx * vx - vy * vy);
        hr[7] = s15 * vx * vz;
        hr[8] = s15h * (vx * vx - vy * vy);
    }
    // in-wave LDS ordering: this wave's ds_writes precede its ds_reads.

    // ---- gather pipeline (2 deep) ----
    const int* srcp = edge_src + (size_t)base * DEG;           // uniform base
    unsigned g0[DEG], g1[DEG];
    #pragma unroll
    for (int k = 0; k < DEG; k++) {
        int s = __builtin_amdgcn_readfirstlane(srcp[k]);       // s_load
        g0[k] = *(const unsigned*)(sbuf + (size_t)s * SROW + 2 * jj);
    }
    #pragma unroll
    for (int i = 0; i < 4; i++) {
        if (i + 1 < 4) {
            #pragma unroll
            for (int k = 0; k < DEG; k++) {
                int s = __builtin_amdgcn_readfirstlane(srcp[(i + 1) * DEG + k]);
                g1[k] = *(const unsigned*)(sbuf + (size_t)s * SROW + 2 * jj);
            }
        }
        const float* hw = &hbf[wid][i][0];
        float acc = 0.f;
        #pragma unroll
        for (int k = 0; k < DEG; k++) {
            const float4 eA = *(const float4*)&ea_t[wid][i][k][0];  // broadcast
            const float4 eB = *(const float4*)&ea_t[wid][i][k][4];
            const float f = hw[k * 12 + code];                      // 9 banks, no conflict
            float we0 = eA.x * wA[0] + eA.y * wA[1] + eA.z * wA[2] + eA.w * wA[3]
                      + eB.x * wA[4] + eB.y * wA[5] + eB.z * wA[6];
            float we1 = eA.x * wB[0] + eA.y * wB[1] + eA.z * wB[2] + eA.w * wB[3]
                      + eB.x * wB[4] + eB.y * wB[5] + eB.z * wB[6];
            acc += f * (bf_lo(g0[k]) * we0 + bf_hi(g0[k]) * we1);
        }
        acc = valid ? acc : 0.f;
        #pragma unroll
        for (int off = 32; off >= 1; off >>= 1) acc += __shfl_xor(acc, off, 64);
        if (lane == 0)
            atomicAdd(out + ((base + i) / 50), acc * 0.035355339059327376f); // 0.25/sqrt(50)
        #pragma unroll
        for (int k = 0; k < DEG; k++) g0[k] = g1[k];
    }
}

extern "C" void kernel_launch(void* const* d_in, const int* in_sizes, int n_in,
                              void* d_out, int out_size, void* d_ws, size_t ws_size,
                              hipStream_t stream) {
    const float* pos  = (const float*)d_in[0];
    const float* x    = (const float*)d_in[1];
    const float* ea   = (const float*)d_in[2];
    const float* W1_0 = (const float*)d_in[3];
    const float* W1_1 = (const float*)d_in[4];
    const float* W1_2 = (const float*)d_in[5];
    const float* W2_0 = (const float*)d_in[6];
    const float* W2_1 = (const float*)d_in[7];
    const float* W2_2 = (const float*)d_in[8];
    const int*   esrc = (const int*)d_in[9];
    float* out = (float*)d_out;

    unsigned short* Wfrag = (unsigned short*)d_ws;                   // 28672 B
    unsigned short* sbuf  = (unsigned short*)((char*)d_ws + 32768);  // 12.8 MB

    hipLaunchKernelGGL(k_prep, dim3(WFRAG_N * 8 / 256), dim3(256), 0, stream,
                       W1_0, W1_1, W1_2, Wfrag, out);
    hipLaunchKernelGGL(k2_s, dim3((N_ATOMS / NPW + 3) / 4), dim3(256), 0, stream,
                       pos, x, ea, esrc, Wfrag, sbuf);
    hipLaunchKernelGGL(k3_fused, dim3(N_ATOMS / 16), dim3(256), 0, stream,
                       pos, ea, esrc, sbuf, W2_0, W2_1, W2_2, out);
}

// Round 14
// 208.093 us; speedup vs baseline: 1.6080x; 1.0002x over previous
//
#include <hip/hip_runtime.h>
#include <hip/hip_bf16.h>

#define N_ATOMS 50000
#define DEG 16
#define N_MOL 1000
#define NA 23
#define NB 7
#define O0 32
#define O1 12
#define O2 8
#define OT 52          // 32+12+8
#define SROW 128       // s-row: 108 used + pad, bf16 (raw ushort bits)
#define NPW 4          // nodes per wave in k2
#define WFRAG_N 1792   // 28 fragments * 64 lanes, short8 each (28672 B)

typedef __attribute__((ext_vector_type(8))) short short8;
typedef __attribute__((ext_vector_type(4))) float floatx4;

__device__ __forceinline__ unsigned short bfbits(float f) {  // f32 -> bf16 RNE
    unsigned u = __float_as_uint(f);
    u += 0x7FFFu + ((u >> 16) & 1u);
    return (unsigned short)(u >> 16);
}
__device__ __forceinline__ float bf_lo(unsigned u) { return __uint_as_float(u << 16); }
__device__ __forceinline__ float bf_hi(unsigned u) { return __uint_as_float(u & 0xFFFF0000u); }
__device__ __forceinline__ float wred4(float v) {  // sum over the 4 quads
    v += __shfl_xor(v, 16, 64); v += __shfl_xor(v, 32, 64); return v;
}

// ---------------- K_prep: zero out + Wfrag + x_bf (bf16, padded) + pos4 ------
__global__ void k_prep(const float* __restrict__ W1_0, const float* __restrict__ W1_1,
                       const float* __restrict__ W1_2, const float* __restrict__ x,
                       const float* __restrict__ pos,
                       unsigned short* __restrict__ Wfrag,
                       unsigned short* __restrict__ x_bf, float4* __restrict__ pos4,
                       float* __restrict__ out) {
    int idx = blockIdx.x * 256 + threadIdx.x;
    if (idx < N_MOL) out[idx] = 0.0f;
    if (idx < WFRAG_N * 8) {
        int j    = idx & 7;
        int lane = (idx >> 3) & 63;
        int st   = idx >> 9;           // 0..27 = s*4+t
        int s = st >> 2, t = st & 3;
        int a = (lane >> 4) * 8 + j, o = t * 16 + (lane & 15);
        float val = 0.f;
        if (a < NA && o < OT) {
            const float n1 = 0.07881104062391006f; // 1/sqrt(23*7)
            if (o < O0)           val = W1_0[(a * NB + s) * O0 + o] * n1;
            else if (o < O0 + O1) val = W1_1[(a * NB + s) * O1 + (o - O0)] * n1;
            else                  val = W1_2[(a * NB + s) * O2 + (o - O0 - O1)] * n1;
        }
        Wfrag[idx] = bfbits(val);
    }
    if (idx < N_ATOMS) {
        float4 p; p.x = pos[idx * 3 + 0]; p.y = pos[idx * 3 + 1];
        p.z = pos[idx * 3 + 2]; p.w = 0.f;
        pos4[idx] = p;
    }
    if (idx < N_ATOMS * 32) {
        int n = idx >> 5, a = idx & 31;
        x_bf[idx] = bfbits((a < NA) ? x[n * NA + a] : 0.f);
    }
}

// ---------------- K2: per-node MFMA GEMM; packed gathers; 5 blocks/CU --------
// R8/R12 lesson: body needs ~48 VGPR; (256,5) cap=102 -> no spill.
// x_bf (3.2MB) fits per-XCD L2 -> gather becomes L2-hit; 1 uint4/lane.
__global__ __launch_bounds__(256, 5) void k2_s(const float4* __restrict__ pos4,
        const unsigned short* __restrict__ x_bf, const float* __restrict__ edge_attr,
        const int* __restrict__ edge_src, const unsigned short* __restrict__ Wfrag,
        unsigned short* __restrict__ sbuf) {
    __shared__ short8 wfrag[WFRAG_N];          // 28672 B, shared by 4 waves
    __shared__ float hbuf[4][16][8];
    const int tid  = threadIdx.x;
    const int wid  = tid >> 6;
    const int lane = tid & 63;
    const int lcol = lane & 15;
    const int quad = lane >> 4;

    {   // cooperative stage of the prebuilt weight fragments (coalesced)
        uint4* dst = (uint4*)wfrag;
        const uint4* src4 = (const uint4*)Wfrag;
        for (int i = tid; i < WFRAG_N; i += 256) dst[i] = src4[i];
    }
    __syncthreads();

    const int wgid = __builtin_amdgcn_readfirstlane(blockIdx.x * 4 + wid);
    const int base = wgid * NPW;
    if (base >= N_ATOMS) return;

    float (*hb)[8] = hbuf[wid];
    const float s3 = 1.7320508075688772f, s15 = 3.872983346207417f;
    const float s5h = 1.118033988749895f, s15h = 1.9364916731037085f;

    auto clampn = [&](int i) { int nn = base + i; return nn < N_ATOMS ? nn : N_ATOMS - 1; };
    int s0v = edge_src[clampn(0) * DEG + lcol];
    int s1v = edge_src[clampn(1) * DEG + lcol];
    uint4 xu0 = *(const uint4*)(x_bf + s0v * 32 + quad * 8);   // 16B aligned
    float4 pp0 = pos4[s0v];
    float e0v[NB];
    {
        const float* p = edge_attr + ((size_t)clampn(0) * DEG + lcol) * NB;
        #pragma unroll
        for (int b = 0; b < NB; b++) e0v[b] = p[b];
    }

    #pragma unroll 1
    for (int i = 0; i < NPW; i++) {
        const int n = base + i;
        if (n >= N_ATOMS) break;
        // ---- prefetch next stage (1 deep: x, ea, pos4(src)) ----
        int s2v = edge_src[clampn(i + 2 < NPW ? i + 2 : i) * DEG + lcol];
        uint4 xu1 = *(const uint4*)(x_bf + s1v * 32 + quad * 8);
        float4 pp1 = pos4[s1v];
        float e1v[NB];
        {
            const float* p = edge_attr + ((size_t)clampn(i + 1 < NPW ? i + 1 : i) * DEG + lcol) * NB;
            #pragma unroll
            for (int b = 0; b < NB; b++) e1v[b] = p[b];
        }
        // ---- unpack this node's x slice (bf16 -> f32, 8 VALU) ----
        float xf[8];
        xf[0] = bf_lo(xu0.x); xf[1] = bf_hi(xu0.x);
        xf[2] = bf_lo(xu0.y); xf[3] = bf_hi(xu0.y);
        xf[4] = bf_lo(xu0.z); xf[5] = bf_hi(xu0.z);
        xf[6] = bf_lo(xu0.w); xf[7] = bf_hi(xu0.w);

        // ---- h-factors for node n (lanes 0..15) ----
        const float4 pd = pos4[n];          // uniform -> s_load_dwordx4
        if (lane < 16) {
            const float vx = pp0.x - pd.x, vy = pp0.y - pd.y, vz = pp0.z - pd.z;
            hb[lane][0] = s3 * vx;  hb[lane][1] = s3 * vy;  hb[lane][2] = s3 * vz;
            hb[lane][3] = s15 * vx * vy;
            hb[lane][4] = s15 * vy * vz;
            hb[lane][5] = s5h * (2.f * vz * vz - vx * vx - vy * vy);
            hb[lane][6] = s15 * vx * vz;
            hb[lane][7] = s15h * (vx * vx - vy * vy);
        }
        // ---- MFMA: 7 K-steps x 4 N-tiles ----
        floatx4 acc0 = {0.f,0.f,0.f,0.f}, acc1 = {0.f,0.f,0.f,0.f};
        floatx4 acc2 = {0.f,0.f,0.f,0.f}, acc3 = {0.f,0.f,0.f,0.f};
        #pragma unroll
        for (int s = 0; s < 7; s++) {
            const float eb = e0v[s];
            union { short8 v; unsigned u[4]; } af;
            #pragma unroll
            for (int j = 0; j < 8; j += 2) {
                float2 pr; pr.x = xf[j] * eb; pr.y = xf[j + 1] * eb;
                __hip_bfloat162 bb = __float22bfloat162_rn(pr);
                af.u[j >> 1] = *(unsigned*)&bb;
            }
            acc0 = __builtin_amdgcn_mfma_f32_16x16x32_bf16(af.v, wfrag[(s*4+0)*64 + lane], acc0, 0, 0, 0);
            acc1 = __builtin_amdgcn_mfma_f32_16x16x32_bf16(af.v, wfrag[(s*4+1)*64 + lane], acc1, 0, 0, 0);
            acc2 = __builtin_amdgcn_mfma_f32_16x16x32_bf16(af.v, wfrag[(s*4+2)*64 + lane], acc2, 0, 0, 0);
            acc3 = __builtin_amdgcn_mfma_f32_16x16x32_bf16(af.v, wfrag[(s*4+3)*64 + lane], acc3, 0, 0, 0);
        }
        // ---- epilogue (layout verified R4): lane's D-edges are e = quad*4+r ----
        float4 hA[4], hB[4];
        #pragma unroll
        for (int r = 0; r < 4; r++) {
            int e = quad * 4 + r;
            hA[r] = *(const float4*)&hb[e][0];
            hB[r] = *(const float4*)&hb[e][4];
        }
        const float q = 0.25f; // inv_sqrt_deg
        unsigned short* sr = sbuf + (size_t)n * SROW;
        float v0 = wred4(acc0[0] + acc0[1] + acc0[2] + acc0[3]);
        float v1 = wred4(acc1[0] + acc1[1] + acc1[2] + acc1[3]);
        if (quad == 0) { sr[lcol] = bfbits(v0 * q); sr[16 + lcol] = bfbits(v1 * q); }
        if (lcol < 12) {
            float t0 = 0.f, t1 = 0.f, t2 = 0.f;
            #pragma unroll
            for (int r = 0; r < 4; r++) {
                float m = acc2[r];
                t0 += m * hA[r].x; t1 += m * hA[r].y; t2 += m * hA[r].z;
            }
            t0 = wred4(t0); t1 = wred4(t1); t2 = wred4(t2);
            if (quad == 0) {
                sr[32 + lcol] = bfbits(t0 * q);
                sr[44 + lcol] = bfbits(t1 * q);
                sr[56 + lcol] = bfbits(t2 * q);
            }
        } else {
            int a = lcol - 12;
            float t0 = 0.f, t1 = 0.f, t2 = 0.f, t3 = 0.f, t4 = 0.f;
            #pragma unroll
            for (int r = 0; r < 4; r++) {
                float m = acc2[r];
                t0 += m * hA[r].w; t1 += m * hB[r].x; t2 += m * hB[r].y;
                t3 += m * hB[r].z; t4 += m * hB[r].w;
            }
            t0 = wred4(t0); t1 = wred4(t1); t2 = wred4(t2); t3 = wred4(t3); t4 = wred4(t4);
            if (quad == 0) {
                sr[68 + a] = bfbits(t0 * q); sr[76 + a] = bfbits(t1 * q);
                sr[84 + a] = bfbits(t2 * q); sr[92 + a] = bfbits(t3 * q);
                sr[100 + a] = bfbits(t4 * q);
            }
        }
        if (lcol < 4) {
            int a = lcol + 4;
            float t0 = 0.f, t1 = 0.f, t2 = 0.f, t3 = 0.f, t4 = 0.f;
            #pragma unroll
            for (int r = 0; r < 4; r++) {
                float m = acc3[r];
                t0 += m * hA[r].w; t1 += m * hB[r].x; t2 += m * hB[r].y;
                t3 += m * hB[r].z; t4 += m * hB[r].w;
            }
            t0 = wred4(t0); t1 = wred4(t1); t2 = wred4(t2); t3 = wred4(t3); t4 = wred4(t4);
            if (quad == 0) {
                sr[68 + a] = bfbits(t0 * q); sr[76 + a] = bfbits(t1 * q);
                sr[84 + a] = bfbits(t2 * q); sr[92 + a] = bfbits(t3 * q);
                sr[100 + a] = bfbits(t4 * q);
            }
        }
        // ---- rotate pipeline ----
        s0v = s1v; s1v = s2v;
        xu0 = xu1; pp0 = pp1;
        #pragma unroll
        for (int b = 0; b < NB; b++) e0v[b] = e1v[b];
    }
}

// ---------------- K3f: R7 body; pos4; hbf stride 10; 8 blocks/CU -------------
__global__ __launch_bounds__(256, 8) void k3_fused(const float4* __restrict__ pos4,
        const float* __restrict__ edge_attr, const int* __restrict__ edge_src,
        const unsigned short* __restrict__ sbuf,
        const float* __restrict__ W2_0, const float* __restrict__ W2_1,
        const float* __restrict__ W2_2, float* __restrict__ out) {
    __shared__ float ea_t[4][4][16][8];    // [wave][node][edge][b(7)+pad]  8 KB
    __shared__ float hbf[4][4][161];       // [wave][node][edge*10 + code]  10.3 KB
    const int tid  = threadIdx.x;
    const int wid  = tid >> 6;
    const int lane = tid & 63;
    const int q    = lane >> 4;
    const int e    = lane & 15;
    const int base = __builtin_amdgcn_readfirstlane(blockIdx.x * 4 + wid) * 4;

    const float c0 = 0.06681531047810609f;  // 1/sqrt(32*7)
    const float c1 = 0.06299407883487121f;  // 1/sqrt(12*7*3)
    const float c2 = 0.05976143046671968f;  // 1/sqrt(8*7*5)
    int code = 0, aA = 0, aB = 0, valid = 1;
    const float* Wb = W2_0; float norm = c0;
    const int j = lane;
    if (j < 16)      { code = 0; aA = 2 * j;   aB = aA + 1; Wb = W2_0; norm = c0; }
    else if (j < 34) { int g = (j - 16) / 6, r = (j - 16) - 6 * g;
                       code = 1 + g; aA = 2 * r; aB = aA + 1; Wb = W2_1; norm = c1; }
    else if (j < 54) { int g = (j - 34) >> 2, r = (j - 34) & 3;
                       code = 4 + g; aA = 2 * r; aB = aA + 1; Wb = W2_2; norm = c2; }
    else             { valid = 0; }
    float wA[NB], wB[NB];
    #pragma unroll
    for (int b = 0; b < NB; b++) {
        wA[b] = valid ? Wb[aA * NB + b] * norm : 0.f;
        wB[b] = valid ? Wb[aB * NB + b] * norm : 0.f;
    }
    const int jj = valid ? j : 0;

    // ---- setup phase: all 64 lanes stage (node q, edge e) ----
    {
        const int nq = base + q;
        const int sE = edge_src[nq * DEG + e];                 // vector load
        const float* eap = edge_attr + ((size_t)nq * DEG + e) * NB;
        float ev[8];
        #pragma unroll
        for (int b = 0; b < NB; b++) ev[b] = eap[b];
        ev[7] = 0.f;
        const float4 ps = pos4[sE];
        const float4 pd = pos4[nq];
        const float vx = ps.x - pd.x, vy = ps.y - pd.y, vz = ps.z - pd.z;
        float* ed = &ea_t[wid][q][e][0];
        *(float4*)(ed)     = *(float4*)&ev[0];
        *(float4*)(ed + 4) = *(float4*)&ev[4];
        const float s3 = 1.7320508075688772f, s15 = 3.872983346207417f;
        const float s5h = 1.118033988749895f, s15h = 1.9364916731037085f;
        float* hr = &hbf[wid][q][e * 10];
        hr[0] = 1.0f;
        hr[1] = s3 * vx; hr[2] = s3 * vy; hr[3] = s3 * vz;
        hr[4] = s15 * vx * vy;
        hr[5] = s15 * vy * vz;
        hr[6] = s5h * (2.f * vz * vz - vx * vx - vy * vy);
        hr[7] = s15 * vx * vz;
        hr[8] = s15h * (vx * vx - vy * vy);
    }
    // in-wave LDS ordering: this wave's ds_writes precede its ds_reads.

    // ---- gather pipeline (2 deep) ----
    const int* srcp = edge_src + (size_t)base * DEG;           // uniform base
    unsigned g0[DEG], g1[DEG];
    #pragma unroll
    for (int k = 0; k < DEG; k++) {
        int s = __builtin_amdgcn_readfirstlane(srcp[k]);       // s_load
        g0[k] = *(const unsigned*)(sbuf + (size_t)s * SROW + 2 * jj);
    }
    #pragma unroll
    for (int i = 0; i < 4; i++) {
        if (i + 1 < 4) {
            #pragma unroll
            for (int k = 0; k < DEG; k++) {
                int s = __builtin_amdgcn_readfirstlane(srcp[(i + 1) * DEG + k]);
                g1[k] = *(const unsigned*)(sbuf + (size_t)s * SROW + 2 * jj);
            }
        }
        const float* hw = &hbf[wid][i][0];
        float acc = 0.f;
        #pragma unroll
        for (int k = 0; k < DEG; k++) {
            const float4 eA = *(const float4*)&ea_t[wid][i][k][0];  // broadcast
            const float4 eB = *(const float4*)&ea_t[wid][i][k][4];
            const float f = hw[k * 10 + code];                      // 9 banks, no conflict
            float we0 = eA.x * wA[0] + eA.y * wA[1] + eA.z * wA[2] + eA.w * wA[3]
                      + eB.x * wA[4] + eB.y * wA[5] + eB.z * wA[6];
            float we1 = eA.x * wB[0] + eA.y * wB[1] + eA.z * wB[2] + eA.w * wB[3]
                      + eB.x * wB[4] + eB.y * wB[5] + eB.z * wB[6];
            acc += f * (bf_lo(g0[k]) * we0 + bf_hi(g0[k]) * we1);
        }
        acc = valid ? acc : 0.f;
        #pragma unroll
        for (int off = 32; off >= 1; off >>= 1) acc += __shfl_xor(acc, off, 64);
        if (lane == 0)
            atomicAdd(out + ((base + i) / 50), acc * 0.035355339059327376f); // 0.25/sqrt(50)
        #pragma unroll
        for (int k = 0; k < DEG; k++) g0[k] = g1[k];
    }
}

extern "C" void kernel_launch(void* const* d_in, const int* in_sizes, int n_in,
                              void* d_out, int out_size, void* d_ws, size_t ws_size,
                              hipStream_t stream) {
    const float* pos  = (const float*)d_in[0];
    const float* x    = (const float*)d_in[1];
    const float* ea   = (const float*)d_in[2];
    const float* W1_0 = (const float*)d_in[3];
    const float* W1_1 = (const float*)d_in[4];
    const float* W1_2 = (const float*)d_in[5];
    const float* W2_0 = (const float*)d_in[6];
    const float* W2_1 = (const float*)d_in[7];
    const float* W2_2 = (const float*)d_in[8];
    const int*   esrc = (const int*)d_in[9];
    float* out = (float*)d_out;

    char* ws = (char*)d_ws;
    unsigned short* Wfrag = (unsigned short*)ws;                         // 28672 B
    unsigned short* sbuf  = (unsigned short*)(ws + 32768);               // 12.8 MB
    unsigned short* x_bf  = (unsigned short*)(ws + 32768 + 12800000);    // 3.2 MB
    float4*         pos4  = (float4*)(ws + 32768 + 12800000 + 3200000);  // 800 KB

    hipLaunchKernelGGL(k_prep, dim3((N_ATOMS * 32 + 255) / 256), dim3(256), 0, stream,
                       W1_0, W1_1, W1_2, x, pos, Wfrag, x_bf, pos4, out);
    hipLaunchKernelGGL(k2_s, dim3((N_ATOMS / NPW + 3) / 4), dim3(256), 0, stream,
                       pos4, x_bf, ea, esrc, Wfrag, sbuf);
    hipLaunchKernelGGL(k3_fused, dim3(N_ATOMS / 16), dim3(256), 0, stream,
                       pos4, ea, esrc, sbuf, W2_0, W2_1, W2_2, out);
}

// Round 15
// 201.113 us; speedup vs baseline: 1.6638x; 1.0347x over previous
//
#include <hip/hip_runtime.h>
#include <hip/hip_bf16.h>

#define N_ATOMS 50000
#define DEG 16
#define N_MOL 1000
#define NA 23
#define NB 7
#define O0 32
#define O1 12
#define O2 8
#define OT 52          // 32+12+8
#define SROW 128       // s-row: 108 used + pad, bf16 (raw ushort bits)
#define NPW 4          // nodes per wave in k2
#define WFRAG_N 1792   // 28 fragments * 64 lanes, short8 each (28672 B)

typedef __attribute__((ext_vector_type(8))) short short8;
typedef __attribute__((ext_vector_type(4))) float floatx4;

__device__ __forceinline__ unsigned short bfbits(float f) {  // f32 -> bf16 RNE
    unsigned u = __float_as_uint(f);
    u += 0x7FFFu + ((u >> 16) & 1u);
    return (unsigned short)(u >> 16);
}
__device__ __forceinline__ float bf_lo(unsigned u) { return __uint_as_float(u << 16); }
__device__ __forceinline__ float bf_hi(unsigned u) { return __uint_as_float(u & 0xFFFF0000u); }
__device__ __forceinline__ float wred4(float v) {  // sum over the 4 quads
    v += __shfl_xor(v, 16, 64); v += __shfl_xor(v, 32, 64); return v;
}

// ---------------- K_prep: zero out + Wfrag + x_bf (bf16, padded) + pos4 ------
__global__ void k_prep(const float* __restrict__ W1_0, const float* __restrict__ W1_1,
                       const float* __restrict__ W1_2, const float* __restrict__ x,
                       const float* __restrict__ pos,
                       unsigned short* __restrict__ Wfrag,
                       unsigned short* __restrict__ x_bf, float4* __restrict__ pos4,
                       float* __restrict__ out) {
    int idx = blockIdx.x * 256 + threadIdx.x;
    if (idx < N_MOL) out[idx] = 0.0f;
    if (idx < WFRAG_N * 8) {
        int j    = idx & 7;
        int lane = (idx >> 3) & 63;
        int st   = idx >> 9;           // 0..27 = s*4+t
        int s = st >> 2, t = st & 3;
        int a = (lane >> 4) * 8 + j, o = t * 16 + (lane & 15);
        float val = 0.f;
        if (a < NA && o < OT) {
            const float n1 = 0.07881104062391006f; // 1/sqrt(23*7)
            if (o < O0)           val = W1_0[(a * NB + s) * O0 + o] * n1;
            else if (o < O0 + O1) val = W1_1[(a * NB + s) * O1 + (o - O0)] * n1;
            else                  val = W1_2[(a * NB + s) * O2 + (o - O0 - O1)] * n1;
        }
        Wfrag[idx] = bfbits(val);
    }
    if (idx < N_ATOMS) {
        float4 p; p.x = pos[idx * 3 + 0]; p.y = pos[idx * 3 + 1];
        p.z = pos[idx * 3 + 2]; p.w = 0.f;
        pos4[idx] = p;
    }
    if (idx < N_ATOMS * 32) {
        int n = idx >> 5, a = idx & 31;
        x_bf[idx] = bfbits((a < NA) ? x[n * NA + a] : 0.f);
    }
}

// ---------------- K2: per-node MFMA GEMM; packed gathers; 5 blocks/CU --------
__global__ __launch_bounds__(256, 5) void k2_s(const float4* __restrict__ pos4,
        const unsigned short* __restrict__ x_bf, const float* __restrict__ edge_attr,
        const int* __restrict__ edge_src, const unsigned short* __restrict__ Wfrag,
        unsigned short* __restrict__ sbuf) {
    __shared__ short8 wfrag[WFRAG_N];          // 28672 B, shared by 4 waves
    __shared__ float hbuf[4][16][8];
    const int tid  = threadIdx.x;
    const int wid  = tid >> 6;
    const int lane = tid & 63;
    const int lcol = lane & 15;
    const int quad = lane >> 4;

    {   // cooperative stage of the prebuilt weight fragments (coalesced)
        uint4* dst = (uint4*)wfrag;
        const uint4* src4 = (const uint4*)Wfrag;
        for (int i = tid; i < WFRAG_N; i += 256) dst[i] = src4[i];
    }
    __syncthreads();

    const int wgid = __builtin_amdgcn_readfirstlane(blockIdx.x * 4 + wid);
    const int base = wgid * NPW;
    if (base >= N_ATOMS) return;

    float (*hb)[8] = hbuf[wid];
    const float s3 = 1.7320508075688772f, s15 = 3.872983346207417f;
    const float s5h = 1.118033988749895f, s15h = 1.9364916731037085f;

    auto clampn = [&](int i) { int nn = base + i; return nn < N_ATOMS ? nn : N_ATOMS - 1; };
    int s0v = edge_src[clampn(0) * DEG + lcol];
    int s1v = edge_src[clampn(1) * DEG + lcol];
    uint4 xu0 = *(const uint4*)(x_bf + s0v * 32 + quad * 8);   // 16B aligned
    float4 pp0 = pos4[s0v];
    float e0v[NB];
    {
        const float* p = edge_attr + ((size_t)clampn(0) * DEG + lcol) * NB;
        #pragma unroll
        for (int b = 0; b < NB; b++) e0v[b] = p[b];
    }

    #pragma unroll 1
    for (int i = 0; i < NPW; i++) {
        const int n = base + i;
        if (n >= N_ATOMS) break;
        // ---- prefetch next stage (1 deep: x, ea, pos4(src)) ----
        int s2v = edge_src[clampn(i + 2 < NPW ? i + 2 : i) * DEG + lcol];
        uint4 xu1 = *(const uint4*)(x_bf + s1v * 32 + quad * 8);
        float4 pp1 = pos4[s1v];
        float e1v[NB];
        {
            const float* p = edge_attr + ((size_t)clampn(i + 1 < NPW ? i + 1 : i) * DEG + lcol) * NB;
            #pragma unroll
            for (int b = 0; b < NB; b++) e1v[b] = p[b];
        }
        // ---- unpack this node's x slice (bf16 -> f32, 8 VALU) ----
        float xf[8];
        xf[0] = bf_lo(xu0.x); xf[1] = bf_hi(xu0.x);
        xf[2] = bf_lo(xu0.y); xf[3] = bf_hi(xu0.y);
        xf[4] = bf_lo(xu0.z); xf[5] = bf_hi(xu0.z);
        xf[6] = bf_lo(xu0.w); xf[7] = bf_hi(xu0.w);

        // ---- h-factors for node n (lanes 0..15) ----
        const float4 pd = pos4[n];          // uniform -> s_load_dwordx4
        if (lane < 16) {
            const float vx = pp0.x - pd.x, vy = pp0.y - pd.y, vz = pp0.z - pd.z;
            hb[lane][0] = s3 * vx;  hb[lane][1] = s3 * vy;  hb[lane][2] = s3 * vz;
            hb[lane][3] = s15 * vx * vy;
            hb[lane][4] = s15 * vy * vz;
            hb[lane][5] = s5h * (2.f * vz * vz - vx * vx - vy * vy);
            hb[lane][6] = s15 * vx * vz;
            hb[lane][7] = s15h * (vx * vx - vy * vy);
        }
        // ---- MFMA: 7 K-steps x 4 N-tiles ----
        floatx4 acc0 = {0.f,0.f,0.f,0.f}, acc1 = {0.f,0.f,0.f,0.f};
        floatx4 acc2 = {0.f,0.f,0.f,0.f}, acc3 = {0.f,0.f,0.f,0.f};
        #pragma unroll
        for (int s = 0; s < 7; s++) {
            const float eb = e0v[s];
            union { short8 v; unsigned u[4]; } af;
            #pragma unroll
            for (int j = 0; j < 8; j += 2) {
                float2 pr; pr.x = xf[j] * eb; pr.y = xf[j + 1] * eb;
                __hip_bfloat162 bb = __float22bfloat162_rn(pr);
                af.u[j >> 1] = *(unsigned*)&bb;
            }
            acc0 = __builtin_amdgcn_mfma_f32_16x16x32_bf16(af.v, wfrag[(s*4+0)*64 + lane], acc0, 0, 0, 0);
            acc1 = __builtin_amdgcn_mfma_f32_16x16x32_bf16(af.v, wfrag[(s*4+1)*64 + lane], acc1, 0, 0, 0);
            acc2 = __builtin_amdgcn_mfma_f32_16x16x32_bf16(af.v, wfrag[(s*4+2)*64 + lane], acc2, 0, 0, 0);
            acc3 = __builtin_amdgcn_mfma_f32_16x16x32_bf16(af.v, wfrag[(s*4+3)*64 + lane], acc3, 0, 0, 0);
        }
        // ---- epilogue (layout verified R4): lane's D-edges are e = quad*4+r ----
        float4 hA[4], hB[4];
        #pragma unroll
        for (int r = 0; r < 4; r++) {
            int e = quad * 4 + r;
            hA[r] = *(const float4*)&hb[e][0];
            hB[r] = *(const float4*)&hb[e][4];
        }
        const float q = 0.25f; // inv_sqrt_deg
        unsigned short* sr = sbuf + (size_t)n * SROW;
        float v0 = wred4(acc0[0] + acc0[1] + acc0[2] + acc0[3]);
        float v1 = wred4(acc1[0] + acc1[1] + acc1[2] + acc1[3]);
        if (quad == 0) { sr[lcol] = bfbits(v0 * q); sr[16 + lcol] = bfbits(v1 * q); }
        if (lcol < 12) {
            float t0 = 0.f, t1 = 0.f, t2 = 0.f;
            #pragma unroll
            for (int r = 0; r < 4; r++) {
                float m = acc2[r];
                t0 += m * hA[r].x; t1 += m * hA[r].y; t2 += m * hA[r].z;
            }
            t0 = wred4(t0); t1 = wred4(t1); t2 = wred4(t2);
            if (quad == 0) {
                sr[32 + lcol] = bfbits(t0 * q);
                sr[44 + lcol] = bfbits(t1 * q);
                sr[56 + lcol] = bfbits(t2 * q);
            }
        } else {
            int a = lcol - 12;
            float t0 = 0.f, t1 = 0.f, t2 = 0.f, t3 = 0.f, t4 = 0.f;
            #pragma unroll
            for (int r = 0; r < 4; r++) {
                float m = acc2[r];
                t0 += m * hA[r].w; t1 += m * hB[r].x; t2 += m * hB[r].y;
                t3 += m * hB[r].z; t4 += m * hB[r].w;
            }
            t0 = wred4(t0); t1 = wred4(t1); t2 = wred4(t2); t3 = wred4(t3); t4 = wred4(t4);
            if (quad == 0) {
                sr[68 + a] = bfbits(t0 * q); sr[76 + a] = bfbits(t1 * q);
                sr[84 + a] = bfbits(t2 * q); sr[92 + a] = bfbits(t3 * q);
                sr[100 + a] = bfbits(t4 * q);
            }
        }
        if (lcol < 4) {
            int a = lcol + 4;
            float t0 = 0.f, t1 = 0.f, t2 = 0.f, t3 = 0.f, t4 = 0.f;
            #pragma unroll
            for (int r = 0; r < 4; r++) {
                float m = acc3[r];
                t0 += m * hA[r].w; t1 += m * hB[r].x; t2 += m * hB[r].y;
                t3 += m * hB[r].z; t4 += m * hB[r].w;
            }
            t0 = wred4(t0); t1 = wred4(t1); t2 = wred4(t2); t3 = wred4(t3); t4 = wred4(t4);
            if (quad == 0) {
                sr[68 + a] = bfbits(t0 * q); sr[76 + a] = bfbits(t1 * q);
                sr[84 + a] = bfbits(t2 * q); sr[92 + a] = bfbits(t3 * q);
                sr[100 + a] = bfbits(t4 * q);
            }
        }
        // ---- rotate pipeline ----
        s0v = s1v; s1v = s2v;
        xu0 = xu1; pp0 = pp1;
        #pragma unroll
        for (int b = 0; b < NB; b++) e0v[b] = e1v[b];
    }
}

// ---------------- K3f: R14 body; back to 7 blocks/CU (R14's (256,8) spilled:
// VGPR clamped 40->32, WRITE 1.6->23.4MB scratch. Cap must exceed ~72 live.) --
__global__ __launch_bounds__(256, 7) void k3_fused(const float4* __restrict__ pos4,
        const float* __restrict__ edge_attr, const int* __restrict__ edge_src,
        const unsigned short* __restrict__ sbuf,
        const float* __restrict__ W2_0, const float* __restrict__ W2_1,
        const float* __restrict__ W2_2, float* __restrict__ out) {
    __shared__ float ea_t[4][4][16][8];    // [wave][node][edge][b(7)+pad]  8 KB
    __shared__ float hbf[4][4][161];       // [wave][node][edge*10 + code]  10.3 KB
    const int tid  = threadIdx.x;
    const int wid  = tid >> 6;
    const int lane = tid & 63;
    const int q    = lane >> 4;
    const int e    = lane & 15;
    const int base = __builtin_amdgcn_readfirstlane(blockIdx.x * 4 + wid) * 4;

    const float c0 = 0.06681531047810609f;  // 1/sqrt(32*7)
    const float c1 = 0.06299407883487121f;  // 1/sqrt(12*7*3)
    const float c2 = 0.05976143046671968f;  // 1/sqrt(8*7*5)
    int code = 0, aA = 0, aB = 0, valid = 1;
    const float* Wb = W2_0; float norm = c0;
    const int j = lane;
    if (j < 16)      { code = 0; aA = 2 * j;   aB = aA + 1; Wb = W2_0; norm = c0; }
    else if (j < 34) { int g = (j - 16) / 6, r = (j - 16) - 6 * g;
                       code = 1 + g; aA = 2 * r; aB = aA + 1; Wb = W2_1; norm = c1; }
    else if (j < 54) { int g = (j - 34) >> 2, r = (j - 34) & 3;
                       code = 4 + g; aA = 2 * r; aB = aA + 1; Wb = W2_2; norm = c2; }
    else             { valid = 0; }
    float wA[NB], wB[NB];
    #pragma unroll
    for (int b = 0; b < NB; b++) {
        wA[b] = valid ? Wb[aA * NB + b] * norm : 0.f;
        wB[b] = valid ? Wb[aB * NB + b] * norm : 0.f;
    }
    const int jj = valid ? j : 0;

    // ---- setup phase: all 64 lanes stage (node q, edge e) ----
    {
        const int nq = base + q;
        const int sE = edge_src[nq * DEG + e];                 // vector load
        const float* eap = edge_attr + ((size_t)nq * DEG + e) * NB;
        float ev[8];
        #pragma unroll
        for (int b = 0; b < NB; b++) ev[b] = eap[b];
        ev[7] = 0.f;
        const float4 ps = pos4[sE];
        const float4 pd = pos4[nq];
        const float vx = ps.x - pd.x, vy = ps.y - pd.y, vz = ps.z - pd.z;
        float* ed = &ea_t[wid][q][e][0];
        *(float4*)(ed)     = *(float4*)&ev[0];
        *(float4*)(ed + 4) = *(float4*)&ev[4];
        const float s3 = 1.7320508075688772f, s15 = 3.872983346207417f;
        const float s5h = 1.118033988749895f, s15h = 1.9364916731037085f;
        float* hr = &hbf[wid][q][e * 10];
        hr[0] = 1.0f;
        hr[1] = s3 * vx; hr[2] = s3 * vy; hr[3] = s3 * vz;
        hr[4] = s15 * vx * vy;
        hr[5] = s15 * vy * vz;
        hr[6] = s5h * (2.f * vz * vz - vx * vx - vy * vy);
        hr[7] = s15 * vx * vz;
        hr[8] = s15h * (vx * vx - vy * vy);
    }
    // in-wave LDS ordering: this wave's ds_writes precede its ds_reads.

    // ---- gather pipeline (2 deep) ----
    const int* srcp = edge_src + (size_t)base * DEG;           // uniform base
    unsigned g0[DEG], g1[DEG];
    #pragma unroll
    for (int k = 0; k < DEG; k++) {
        int s = __builtin_amdgcn_readfirstlane(srcp[k]);       // s_load
        g0[k] = *(const unsigned*)(sbuf + (size_t)s * SROW + 2 * jj);
    }
    #pragma unroll
    for (int i = 0; i < 4; i++) {
        if (i + 1 < 4) {
            #pragma unroll
            for (int k = 0; k < DEG; k++) {
                int s = __builtin_amdgcn_readfirstlane(srcp[(i + 1) * DEG + k]);
                g1[k] = *(const unsigned*)(sbuf + (size_t)s * SROW + 2 * jj);
            }
        }
        const float* hw = &hbf[wid][i][0];
        float acc = 0.f;
        #pragma unroll
        for (int k = 0; k < DEG; k++) {
            const float4 eA = *(const float4*)&ea_t[wid][i][k][0];  // broadcast
            const float4 eB = *(const float4*)&ea_t[wid][i][k][4];
            const float f = hw[k * 10 + code];                      // 9 banks, no conflict
            float we0 = eA.x * wA[0] + eA.y * wA[1] + eA.z * wA[2] + eA.w * wA[3]
                      + eB.x * wA[4] + eB.y * wA[5] + eB.z * wA[6];
            float we1 = eA.x * wB[0] + eA.y * wB[1] + eA.z * wB[2] + eA.w * wB[3]
                      + eB.x * wB[4] + eB.y * wB[5] + eB.z * wB[6];
            acc += f * (bf_lo(g0[k]) * we0 + bf_hi(g0[k]) * we1);
        }
        acc = valid ? acc : 0.f;
        #pragma unroll
        for (int off = 32; off >= 1; off >>= 1) acc += __shfl_xor(acc, off, 64);
        if (lane == 0)
            atomicAdd(out + ((base + i) / 50), acc * 0.035355339059327376f); // 0.25/sqrt(50)
        #pragma unroll
        for (int k = 0; k < DEG; k++) g0[k] = g1[k];
    }
}

extern "C" void kernel_launch(void* const* d_in, const int* in_sizes, int n_in,
                              void* d_out, int out_size, void* d_ws, size_t ws_size,
                              hipStream_t stream) {
    const float* pos  = (const float*)d_in[0];
    const float* x    = (const float*)d_in[1];
    const float* ea   = (const float*)d_in[2];
    const float* W1_0 = (const float*)d_in[3];
    const float* W1_1 = (const float*)d_in[4];
    const float* W1_2 = (const float*)d_in[5];
    const float* W2_0 = (const float*)d_in[6];
    const float* W2_1 = (const float*)d_in[7];
    const float* W2_2 = (const float*)d_in[8];
    const int*   esrc = (const int*)d_in[9];
    float* out = (float*)d_out;

    char* ws = (char*)d_ws;
    unsigned short* Wfrag = (unsigned short*)ws;                         // 28672 B
    unsigned short* sbuf  = (unsigned short*)(ws + 32768);               // 12.8 MB
    unsigned short* x_bf  = (unsigned short*)(ws + 32768 + 12800000);    // 3.2 MB
    float4*         pos4  = (float4*)(ws + 32768 + 12800000 + 3200000);  // 800 KB

    hipLaunchKernelGGL(k_prep, dim3((N_ATOMS * 32 + 255) / 256), dim3(256), 0, stream,
                       W1_0, W1_1, W1_2, x, pos, Wfrag, x_bf, pos4, out);
    hipLaunchKernelGGL(k2_s, dim3((N_ATOMS / NPW + 3) / 4), dim3(256), 0, stream,
                       pos4, x_bf, ea, esrc, Wfrag, sbuf);
    hipLaunchKernelGGL(k3_fused, dim3(N_ATOMS / 16), dim3(256), 0, stream,
                       pos4, ea, esrc, sbuf, W2_0, W2_1, W2_2, out);
}